// Round 7
// baseline (1578.988 us; speedup 1.0000x reference)
//
#include <hip/hip_runtime.h>
#include <hip/hip_bf16.h>
#include <math.h>

// NTM forward, fully fused: one block per batch element, T=64 steps in-kernel.
// Rev 8: COALESCED multi-output GEMVs.
// Round-6 post-mortem: spill removal barely helped; the dominant stall is the
// row-per-thread GEMV on transposed weights -- each wave-level 16B load hits
// 64 distinct cache lines (256-512B stride between lanes) => ~64 cy of L1
// segment processing per load instruction, ~15k cy/step across 8 waves, plus
// phase imbalance (j<70 threads did 2x GEMV work).
// New scheme: each thread computes 8 ADJACENT outputs, loading W[i][j0..j0+7]
// from ROW-MAJOR weights: consecutive lanes -> consecutive 16B chunks (1KB
// contiguous per wave-load, 16 segments not 64), 8 independent FMA chains,
// xor-shuffle partial reduce, perfectly balanced phases.
// Wc [128][256] and Wf [320][64] are used in ORIGINAL layout (rows 16B-aligned,
// no repack). Ww/Wr repacked only to pad rows: [256][256] / [256][128].
// M stays hierarchical (reg row + LDS row) from round 6: VGPR=128, no spill.

constexpr int kB  = 64;
constexpr int kT  = 64;
constexpr int kIN = 64;
constexpr int kC  = 256;
constexpr int kN  = 1024;
constexpr int kMV = 64;
constexpr int kOUT = 64;
constexpr int kHW = 198;   // write head raw dim: MV+6+2*MV
constexpr int kHR = 70;    // read head raw dim: MV+6
constexpr int NT  = 512;   // threads per block (8 waves)
constexpr int NW  = NT / 64;
constexpr float kEPS = 1e-8f;

// packed (padded row-major) head weights, offsets in elements
constexpr int kPWwOff = 0;                 // Ww padded [256][256]
constexpr int kPWrOff = kC * 256;          // Wr padded [256][128] @ 65536
constexpr int kPTotal = kPWrOff + kC * 128;  // 98304 elements
constexpr size_t kWsNeeded = 256 + (size_t)kPTotal * 4;  // fp32 worst case

__device__ __forceinline__ float ldf(const float* p, int i) { return p[i]; }
__device__ __forceinline__ float ldf(const __hip_bfloat16* p, int i) { return __bfloat162float(p[i]); }
__device__ __forceinline__ void stf(float* p, int i, float v) { p[i] = v; }
__device__ __forceinline__ void stf(__hip_bfloat16* p, int i, float v) { p[i] = __float2bfloat16(v); }

// 8 contiguous elements -> float[8]; 16B-aligned by construction.
__device__ __forceinline__ void ld8(const __hip_bfloat16* p, float* f) {
  uint4 u = *reinterpret_cast<const uint4*>(p);
  f[0] = __uint_as_float(u.x << 16); f[1] = __uint_as_float(u.x & 0xffff0000u);
  f[2] = __uint_as_float(u.y << 16); f[3] = __uint_as_float(u.y & 0xffff0000u);
  f[4] = __uint_as_float(u.z << 16); f[5] = __uint_as_float(u.z & 0xffff0000u);
  f[6] = __uint_as_float(u.w << 16); f[7] = __uint_as_float(u.w & 0xffff0000u);
}
__device__ __forceinline__ void ld8(const float* p, float* f) {
  float4 a = reinterpret_cast<const float4*>(p)[0];
  float4 b = reinterpret_cast<const float4*>(p)[1];
  f[0] = a.x; f[1] = a.y; f[2] = a.z; f[3] = a.w;
  f[4] = b.x; f[5] = b.y; f[6] = b.z; f[7] = b.w;
}

__device__ __forceinline__ float fexp(float v) { return __expf(v); }
__device__ __forceinline__ float sigmoidf_(float v) {
  return __fdividef(1.f, 1.f + __expf(-v));
}
__device__ __forceinline__ float softplusf_(float v) {
  return v > 20.f ? v : __logf(1.f + __expf(v));
}
__device__ __forceinline__ float ftanh(float v) {
  float a = fminf(fabsf(v), 15.f);          // tanh(15) == 1 in fp32
  float e = __expf(2.f * a);
  float t = 1.f - __fdividef(2.f, e + 1.f);
  return v < 0.f ? -t : t;
}

__device__ __forceinline__ float wsum(float v) {
  v += __shfl_xor(v, 32); v += __shfl_xor(v, 16); v += __shfl_xor(v, 8);
  v += __shfl_xor(v, 4);  v += __shfl_xor(v, 2);  v += __shfl_xor(v, 1);
  return v;
}
__device__ __forceinline__ float wmax(float v) {
  v = fmaxf(v, __shfl_xor(v, 32)); v = fmaxf(v, __shfl_xor(v, 16));
  v = fmaxf(v, __shfl_xor(v, 8));  v = fmaxf(v, __shfl_xor(v, 4));
  v = fmaxf(v, __shfl_xor(v, 2));  v = fmaxf(v, __shfl_xor(v, 1));
  return v;
}

struct alignas(16) Smem {
  // M rows 512..1023: [block b=col/4][row r][4 floats]; lane-contiguous b128.
  float M1s[16 * 512 * 4];   // 128 KB
  float partA[3072];         // partials arena: ctrl 8x256 | heads 8x256 + 8x128
  float E[kN];               // unnormalized content softmax numerators
  float WP[kN];              // previous weights (for shift conv)
  float in[kIN + kMV];       // controller input [x_t | r_{t-1}]
  float cr[kC + kMV];        // output-FC input [c | r_t]
  float k[kMV], kr[kMV], e[kMV], a[kMV];
  float bcS[kC], bwS[kHW], brS[kHR], bfS[kOUT];   // biases (staged once)
  float red[3][NW];          // cross-wave reduction slots
  float scal[16];            // 0..6 write head; 8..14 read head
};
static_assert(sizeof(Smem) <= 160 * 1024, "LDS budget");

__device__ __forceinline__ int m1idx(int blk, int row) { return (blk * 512 + row) * 4; }

// Two rows per thread (reg row sim0, LDS row sim1); 3 barriers. E/WP written
// before the gsum barrier; wg for shifted neighbors recomputed from E/WP with
// the identical fmaf expression -> bit-identical.
__device__ __forceinline__ void address2(Smem& sm, int tid, int lane, int wid,
                                         float sim0, float sim1,
                                         float g, float s0, float s1, float s2, float gamma,
                                         float wp0, float wp1,
                                         float& w0, float& w1) {
  float m = wmax(fmaxf(sim0, sim1));
  if (lane == 0) sm.red[0][wid] = m;
  __syncthreads();                                   // A
  float gmax = sm.red[0][0];
  #pragma unroll
  for (int i = 1; i < NW; ++i) gmax = fmaxf(gmax, sm.red[0][i]);
  float e0 = fexp(sim0 - gmax), e1 = fexp(sim1 - gmax);
  sm.E[tid] = e0; sm.E[tid + NT] = e1;
  sm.WP[tid] = wp0; sm.WP[tid + NT] = wp1;
  float sv = wsum(e0 + e1);
  if (lane == 0) sm.red[1][wid] = sv;
  __syncthreads();                                   // B (covers gsum AND E/WP)
  float gsum = 0.f;
  #pragma unroll
  for (int i = 0; i < NW; ++i) gsum += sm.red[1][i];
  float inv = __fdividef(1.f, gsum);
  float wg0 = fmaf(g, fmaf(e0, inv, -wp0), wp0);
  float wg1 = fmaf(g, fmaf(e1, inv, -wp1), wp1);
  // circular conv: s0*w[n+1] + s1*w[n] + s2*w[n-1]  (SHIFTS = -1,0,+1)
  int np = (tid + 1) & (kN - 1), nm = (tid + kN - 1) & (kN - 1);
  float wgp = fmaf(g, fmaf(sm.E[np], inv, -sm.WP[np]), sm.WP[np]);
  float wgm = fmaf(g, fmaf(sm.E[nm], inv, -sm.WP[nm]), sm.WP[nm]);
  float ws0 = s0 * wgp + s1 * wg0 + s2 * wgm;
  int npb = (tid + NT + 1) & (kN - 1), nmb = (tid + NT - 1) & (kN - 1);
  float wgpb = fmaf(g, fmaf(sm.E[npb], inv, -sm.WP[npb]), sm.WP[npb]);
  float wgmb = fmaf(g, fmaf(sm.E[nmb], inv, -sm.WP[nmb]), sm.WP[nmb]);
  float ws1 = s0 * wgpb + s1 * wg1 + s2 * wgmb;
  float p0 = fexp(gamma * __logf(ws0 + kEPS));
  float p1 = fexp(gamma * __logf(ws1 + kEPS));
  float pv = wsum(p0 + p1);
  if (lane == 0) sm.red[2][wid] = pv;
  __syncthreads();                                   // C
  float psum = 0.f;
  #pragma unroll
  for (int i = 0; i < NW; ++i) psum += sm.red[2][i];
  float ipn = __fdividef(1.f, psum);
  w0 = p0 * ipn; w1 = p1 * ipn;
}

// flag: 1 if buffers are bf16, 0 if fp32.  w_bias is a softmax -> sums to 1.
__global__ void detect_dtype(const void* wb, int* flag) {
  const unsigned short* u = (const unsigned short*)wb;
  int lane = threadIdx.x;
  float s = 0.f;
  for (int i = lane; i < kN; i += 64)
    s += __uint_as_float(((unsigned int)u[i]) << 16);
  s = wsum(s);
  if (lane == 0 && blockIdx.x == 0)
    *flag = (s > 0.75f && s < 1.25f) ? 1 : 0;
}

// Pad-repack Ww [256][198] -> [256][256] and Wr [256][70] -> [256][128].
template <typename TD, int WANT>
__global__ void repack_w(const TD* __restrict__ Ww, const TD* __restrict__ Wr,
                         TD* __restrict__ pk, const int* __restrict__ flag) {
  if (*flag != WANT) return;
  for (int idx = blockIdx.x * blockDim.x + threadIdx.x; idx < kPTotal;
       idx += gridDim.x * blockDim.x) {
    TD v = (TD)0.0f;
    if (idx < kPWrOff) {                     // Ww pad
      int i = idx >> 8, j = idx & 255;
      if (j < kHW) v = Ww[i * kHW + j];
    } else {                                 // Wr pad
      int r = idx - kPWrOff;
      int i = r >> 7, j = r & 127;
      if (j < kHR) v = Wr[i * kHR + j];
    }
    pk[idx] = v;
  }
}

template <typename TD, int WANT, int PACKED>
__global__ __launch_bounds__(NT, 1) void ntm_fused(
    const TD* __restrict__ x,
    const TD* __restrict__ Wc, const TD* __restrict__ bc,
    const TD* __restrict__ Wr, const TD* __restrict__ br,
    const TD* __restrict__ Ww, const TD* __restrict__ bw,
    const TD* __restrict__ Wf, const TD* __restrict__ bf,
    const TD* __restrict__ r_bias, const TD* __restrict__ w_bias,
    const TD* __restrict__ M_bias,
    const TD* __restrict__ pk,
    TD* __restrict__ out, const int* __restrict__ flag) {
  if (*flag != WANT) return;
  __shared__ Smem sm;
  const int tid  = threadIdx.x;
  const int b    = blockIdx.x;
  const int lane = tid & 63;
  const int wid  = tid >> 6;

  const TD* pWw = pk + kPWwOff;
  const TD* pWr = pk + kPWrOff;

  // ---- one-time staging: biases, r_bias, x_0
  if (tid < kC)  sm.bcS[tid] = ldf(bc, tid);
  if (tid < kHW) sm.bwS[tid] = ldf(bw, tid);
  if (tid < kHR) sm.brS[tid] = ldf(br, tid);
  if (tid < kOUT) sm.bfS[tid] = ldf(bf, tid);
  if (tid < kMV) {
    float rv = ldf(r_bias, tid);
    sm.in[kIN + tid] = rv;
    sm.cr[kC + tid] = rv;
  }
  if (tid < 8) {
    float f[8]; ld8(x + (size_t)b * kT * kIN + tid * 8, f);
    #pragma unroll
    for (int u = 0; u < 8; ++u) sm.in[tid * 8 + u] = f[u];
  }

  // ---- init state: reg row (tid) + LDS row (tid+512), norms, prev weights
  float M0[kMV];
  float n2_0 = 0.f, n2_1 = 0.f;
  #pragma unroll
  for (int jb = 0; jb < kMV; jb += 8) {
    float f0[8], f1[8];
    ld8(M_bias + (size_t)tid * kMV + jb, f0);
    ld8(M_bias + (size_t)(tid + NT) * kMV + jb, f1);
    #pragma unroll
    for (int u = 0; u < 8; ++u) {
      M0[jb + u] = f0[u];
      n2_0 = fmaf(f0[u], f0[u], n2_0);
      n2_1 = fmaf(f1[u], f1[u], n2_1);
    }
    *(float4*)&sm.M1s[m1idx(jb >> 2, tid)] = make_float4(f1[0], f1[1], f1[2], f1[3]);
    *(float4*)&sm.M1s[m1idx((jb >> 2) + 1, tid)] = make_float4(f1[4], f1[5], f1[6], f1[7]);
  }
  float wp0 = ldf(w_bias, tid);
  float wp1 = ldf(w_bias, tid + NT);
  __syncthreads();

  #pragma unroll 1
  for (int t = 0; t < kT; ++t) {
    // ---- controller GEMV (coalesced): in[128] @ Wc[128][256]
    // thread (ip=tid>>5, jc=tid&31): outputs jc*8..+7, i-range ip*8..+7.
    // Lanes 0-31 of a wave read one contiguous 512B row chunk -> coalesced.
    {
      const int jc = tid & 31, ip = tid >> 5;
      const int i0 = ip * 8;
      float acc[8] = {0.f, 0.f, 0.f, 0.f, 0.f, 0.f, 0.f, 0.f};
      #pragma unroll
      for (int u = 0; u < 8; ++u) {
        float f[8]; ld8(Wc + (i0 + u) * kC + jc * 8, f);
        float xv = sm.in[i0 + u];
        #pragma unroll
        for (int v = 0; v < 8; ++v) acc[v] = fmaf(xv, f[v], acc[v]);
      }
      #pragma unroll
      for (int v = 0; v < 8; ++v) acc[v] += __shfl_xor(acc[v], 32);
      if (lane < 32) {
        *(float4*)&sm.partA[wid * 256 + jc * 8]     = make_float4(acc[0], acc[1], acc[2], acc[3]);
        *(float4*)&sm.partA[wid * 256 + jc * 8 + 4] = make_float4(acc[4], acc[5], acc[6], acc[7]);
      }
    }
    __syncthreads();                                               // 1
    if (tid < kC) {
      float s = sm.bcS[tid];
      #pragma unroll
      for (int w = 0; w < NW; ++w) s += sm.partA[w * 256 + tid];
      sm.cr[tid] = ftanh(s);
    }
    __syncthreads();                                               // 2

    // ---- head GEMVs (coalesced, balanced): c[256] @ Ww_pad[256][256], then
    //      c[256] @ Wr_pad[256][128]. All threads active in both.
    {
      // Ww: thread (ip=tid>>5 covers 16 i, jc=tid&31 covers 8 j)
      const int jc = tid & 31, ip = tid >> 5;
      const int i0 = ip * 16;
      float acc[8] = {0.f, 0.f, 0.f, 0.f, 0.f, 0.f, 0.f, 0.f};
      if constexpr (PACKED) {
        #pragma unroll
        for (int u = 0; u < 16; ++u) {
          float f[8]; ld8(pWw + (i0 + u) * 256 + jc * 8, f);
          float cv = sm.cr[i0 + u];
          #pragma unroll
          for (int v = 0; v < 8; ++v) acc[v] = fmaf(cv, f[v], acc[v]);
        }
      } else {
        #pragma unroll 4
        for (int u = 0; u < 16; ++u) {
          float cv = sm.cr[i0 + u];
          #pragma unroll
          for (int v = 0; v < 8; ++v) {
            int j = jc * 8 + v;
            float wv = (j < kHW) ? ldf(Ww, (i0 + u) * kHW + j) : 0.f;
            acc[v] = fmaf(cv, wv, acc[v]);
          }
        }
      }
      #pragma unroll
      for (int v = 0; v < 8; ++v) acc[v] += __shfl_xor(acc[v], 32);
      if (lane < 32) {
        *(float4*)&sm.partA[wid * 256 + jc * 8]     = make_float4(acc[0], acc[1], acc[2], acc[3]);
        *(float4*)&sm.partA[wid * 256 + jc * 8 + 4] = make_float4(acc[4], acc[5], acc[6], acc[7]);
      }
      // Wr: thread (ip2=tid>>4 covers 8 i, jc2=tid&15 covers 8 j)
      const int jc2 = tid & 15, ip2 = tid >> 4;
      const int i02 = ip2 * 8;
      float ac2[8] = {0.f, 0.f, 0.f, 0.f, 0.f, 0.f, 0.f, 0.f};
      if constexpr (PACKED) {
        #pragma unroll
        for (int u = 0; u < 8; ++u) {
          float f[8]; ld8(pWr + (i02 + u) * 128 + jc2 * 8, f);
          float cv = sm.cr[i02 + u];
          #pragma unroll
          for (int v = 0; v < 8; ++v) ac2[v] = fmaf(cv, f[v], ac2[v]);
        }
      } else {
        #pragma unroll 4
        for (int u = 0; u < 8; ++u) {
          float cv = sm.cr[i02 + u];
          #pragma unroll
          for (int v = 0; v < 8; ++v) {
            int j = jc2 * 8 + v;
            float wv = (j < kHR) ? ldf(Wr, (i02 + u) * kHR + j) : 0.f;
            ac2[v] = fmaf(cv, wv, ac2[v]);
          }
        }
      }
      #pragma unroll
      for (int v = 0; v < 8; ++v) {
        ac2[v] += __shfl_xor(ac2[v], 16);
        ac2[v] += __shfl_xor(ac2[v], 32);
      }
      if ((lane & 48) == 0) {   // lanes 0..15
        *(float4*)&sm.partA[2048 + wid * 128 + jc2 * 8]     = make_float4(ac2[0], ac2[1], ac2[2], ac2[3]);
        *(float4*)&sm.partA[2048 + wid * 128 + jc2 * 8 + 4] = make_float4(ac2[4], ac2[5], ac2[6], ac2[7]);
      }
    }
    __syncthreads();                                               // 3

    // ---- head reduce + params (balanced wave-uniform branches)
    {
      auto redW = [&](int j) {
        float s = sm.bwS[j];
        #pragma unroll
        for (int w = 0; w < NW; ++w) s += sm.partA[w * 256 + j];
        return s;
      };
      auto redR = [&](int j) {
        float s = sm.brS[j];
        #pragma unroll
        for (int w = 0; w < NW; ++w) s += sm.partA[2048 + w * 128 + j];
        return s;
      };
      if (wid == 0) {                       // write key + |k|
        float kv = ftanh(redW(lane));
        sm.k[lane] = kv;
        float s = wsum(kv * kv);
        if (lane == 0) sm.scal[6] = sqrtf(s);
      } else if (wid == 1) {                // erase
        sm.e[lane] = sigmoidf_(redW(70 + lane));
      } else if (wid == 2) {                // add
        sm.a[lane] = ftanh(redW(134 + lane));
      } else if (wid == 3) {                // read key + |k|
        float kv = ftanh(redR(lane));
        sm.kr[lane] = kv;
        float s = wsum(kv * kv);
        if (lane == 0) sm.scal[14] = sqrtf(s);
      } else if (tid == 256) {              // write head: beta, g, gamma
        sm.scal[0] = softplusf_(redW(64));
        sm.scal[1] = sigmoidf_(redW(65));
        sm.scal[2] = 1.f + softplusf_(redW(69));
      } else if (tid == 257) {              // write head: shift softmax
        float a0 = redW(66), a1 = redW(67), a2 = redW(68);
        float mx = fmaxf(a0, fmaxf(a1, a2));
        float e0 = fexp(a0 - mx), e1 = fexp(a1 - mx), e2 = fexp(a2 - mx);
        float d = __fdividef(1.f, e0 + e1 + e2);
        sm.scal[3] = e0 * d; sm.scal[4] = e1 * d; sm.scal[5] = e2 * d;
      } else if (tid == 320) {              // read head: beta, g, gamma
        sm.scal[8]  = softplusf_(redR(64));
        sm.scal[9]  = sigmoidf_(redR(65));
        sm.scal[10] = 1.f + softplusf_(redR(69));
      } else if (tid == 321) {              // read head: shift softmax
        float a0 = redR(66), a1 = redR(67), a2 = redR(68);
        float mx = fmaxf(a0, fmaxf(a1, a2));
        float e0 = fexp(a0 - mx), e1 = fexp(a1 - mx), e2 = fexp(a2 - mx);
        float d = __fdividef(1.f, e0 + e1 + e2);
        sm.scal[11] = e0 * d; sm.scal[12] = e1 * d; sm.scal[13] = e2 * d;
      }
    }
    __syncthreads();                                               // 4

    // ---- write head addressing (reg row + LDS row dots)
    float ww0, ww1;
    {
      float beta = sm.scal[0], g = sm.scal[1], gamma = sm.scal[2];
      float s0 = sm.scal[3], s1 = sm.scal[4], s2 = sm.scal[5], kn = sm.scal[6];
      float d0 = 0.f, d1 = 0.f;
      #pragma unroll
      for (int bq = 0; bq < 16; ++bq) {
        float4 kv = *(const float4*)&sm.k[bq * 4];
        d0 = fmaf(M0[bq * 4],     kv.x, d0);
        d0 = fmaf(M0[bq * 4 + 1], kv.y, d0);
        d0 = fmaf(M0[bq * 4 + 2], kv.z, d0);
        d0 = fmaf(M0[bq * 4 + 3], kv.w, d0);
        float4 mv = *(const float4*)&sm.M1s[m1idx(bq, tid)];
        d1 = fmaf(mv.x, kv.x, d1); d1 = fmaf(mv.y, kv.y, d1);
        d1 = fmaf(mv.z, kv.z, d1); d1 = fmaf(mv.w, kv.w, d1);
      }
      float sim0 = beta * d0 / (sqrtf(n2_0) * kn + kEPS);
      float sim1 = beta * d1 / (sqrtf(n2_1) * kn + kEPS);
      address2(sm, tid, lane, wid, sim0, sim1, g, s0, s1, s2, gamma, wp0, wp1, ww0, ww1);
    }                                                              // 5,6,7

    // ---- memory update, fused with read-head dot + new row norms
    float dr0 = 0.f, dr1 = 0.f, nn0 = 0.f, nn1 = 0.f;
    #pragma unroll
    for (int bq = 0; bq < 16; ++bq) {
      float4 ev = *(const float4*)&sm.e[bq * 4];
      float4 av = *(const float4*)&sm.a[bq * 4];
      float4 kv = *(const float4*)&sm.kr[bq * 4];
      {
        float m = fmaf(ww0, fmaf(-ev.x, M0[bq * 4], av.x), M0[bq * 4]);
        M0[bq * 4] = m; dr0 = fmaf(m, kv.x, dr0); nn0 = fmaf(m, m, nn0);
      }
      {
        float m = fmaf(ww0, fmaf(-ev.y, M0[bq * 4 + 1], av.y), M0[bq * 4 + 1]);
        M0[bq * 4 + 1] = m; dr0 = fmaf(m, kv.y, dr0); nn0 = fmaf(m, m, nn0);
      }
      {
        float m = fmaf(ww0, fmaf(-ev.z, M0[bq * 4 + 2], av.z), M0[bq * 4 + 2]);
        M0[bq * 4 + 2] = m; dr0 = fmaf(m, kv.z, dr0); nn0 = fmaf(m, m, nn0);
      }
      {
        float m = fmaf(ww0, fmaf(-ev.w, M0[bq * 4 + 3], av.w), M0[bq * 4 + 3]);
        M0[bq * 4 + 3] = m; dr0 = fmaf(m, kv.w, dr0); nn0 = fmaf(m, m, nn0);
      }
      int fi = m1idx(bq, tid);
      float4 mv = *(const float4*)&sm.M1s[fi];
      float4 nm;
      nm.x = fmaf(ww1, fmaf(-ev.x, mv.x, av.x), mv.x);
      dr1 = fmaf(nm.x, kv.x, dr1); nn1 = fmaf(nm.x, nm.x, nn1);
      nm.y = fmaf(ww1, fmaf(-ev.y, mv.y, av.y), mv.y);
      dr1 = fmaf(nm.y, kv.y, dr1); nn1 = fmaf(nm.y, nm.y, nn1);
      nm.z = fmaf(ww1, fmaf(-ev.z, mv.z, av.z), mv.z);
      dr1 = fmaf(nm.z, kv.z, dr1); nn1 = fmaf(nm.z, nm.z, nn1);
      nm.w = fmaf(ww1, fmaf(-ev.w, mv.w, av.w), mv.w);
      dr1 = fmaf(nm.w, kv.w, dr1); nn1 = fmaf(nm.w, nm.w, nn1);
      *(float4*)&sm.M1s[fi] = nm;
    }

    // ---- read head addressing (prev weights = write weights)
    float wr0, wr1;
    {
      float beta = sm.scal[8], g = sm.scal[9], gamma = sm.scal[10];
      float s0 = sm.scal[11], s1 = sm.scal[12], s2 = sm.scal[13], kn = sm.scal[14];
      float sim0 = beta * dr0 / (sqrtf(nn0) * kn + kEPS);
      float sim1 = beta * dr1 / (sqrtf(nn1) * kn + kEPS);
      address2(sm, tid, lane, wid, sim0, sim1, g, s0, s1, s2, gamma, ww0, ww1, wr0, wr1);
    }                                                              // 8,9,10
    wp0 = wr0; wp1 = wr1; n2_0 = nn0; n2_1 = nn1;   // carry state

    // ---- read vector r[j] = sum_n w_r[n] M[n][j]
    // two 32-column butterfly passes; register peak cur[16].
    {
      // pass A: columns 0..31
      {
        float cur[16];
        const int b0 = lane & 1;
        #pragma unroll
        for (int qq = 0; qq < 8; ++qq) {
          float4 mv = *(const float4*)&sm.M1s[m1idx(qq, tid)];
          float v0 = fmaf(wr0, M0[4 * qq],     wr1 * mv.x);
          float v1 = fmaf(wr0, M0[4 * qq + 1], wr1 * mv.y);
          float keep = b0 ? v1 : v0, send = b0 ? v0 : v1;
          cur[2 * qq] = keep + __shfl_xor(send, 1);
          float v2 = fmaf(wr0, M0[4 * qq + 2], wr1 * mv.z);
          float v3 = fmaf(wr0, M0[4 * qq + 3], wr1 * mv.w);
          keep = b0 ? v3 : v2; send = b0 ? v2 : v3;
          cur[2 * qq + 1] = keep + __shfl_xor(send, 1);
        }
        #pragma unroll
        for (int st = 1; st < 5; ++st) {
          const int d = 1 << st;
          const int bb = (lane >> st) & 1;
          #pragma unroll
          for (int q = 0; q < (16 >> st); ++q) {
            float x0 = cur[2 * q], x1 = cur[2 * q + 1];
            float keep = bb ? x1 : x0, send = bb ? x0 : x1;
            cur[q] = keep + __shfl_xor(send, d);
          }
        }
        float tot = cur[0] + __shfl_xor(cur[0], 32);
        if (lane < 32) sm.partA[wid * 64 + lane] = tot;
      }
      // pass B: columns 32..63
      {
        float cur[16];
        const int b0 = lane & 1;
        #pragma unroll
        for (int qq = 0; qq < 8; ++qq) {
          float4 mv = *(const float4*)&sm.M1s[m1idx(8 + qq, tid)];
          float v0 = fmaf(wr0, M0[32 + 4 * qq],     wr1 * mv.x);
          float v1 = fmaf(wr0, M0[32 + 4 * qq + 1], wr1 * mv.y);
          float keep = b0 ? v1 : v0, send = b0 ? v0 : v1;
          cur[2 * qq] = keep + __shfl_xor(send, 1);
          float v2 = fmaf(wr0, M0[32 + 4 * qq + 2], wr1 * mv.z);
          float v3 = fmaf(wr0, M0[32 + 4 * qq + 3], wr1 * mv.w);
          keep = b0 ? v3 : v2; send = b0 ? v2 : v3;
          cur[2 * qq + 1] = keep + __shfl_xor(send, 1);
        }
        #pragma unroll
        for (int st = 1; st < 5; ++st) {
          const int d = 1 << st;
          const int bb = (lane >> st) & 1;
          #pragma unroll
          for (int q = 0; q < (16 >> st); ++q) {
            float x0 = cur[2 * q], x1 = cur[2 * q + 1];
            float keep = bb ? x1 : x0, send = bb ? x0 : x1;
            cur[q] = keep + __shfl_xor(send, d);
          }
        }
        float tot = cur[0] + __shfl_xor(cur[0], 32);
        if (lane < 32) sm.partA[wid * 64 + 32 + lane] = tot;
      }
    }
    __syncthreads();                                               // 11
    if (tid < kMV) {
      float s = sm.partA[tid];
      #pragma unroll
      for (int w = 1; w < NW; ++w) s += sm.partA[w * 64 + tid];
      sm.cr[kC + tid] = s;     // output-FC input
      sm.in[kIN + tid] = s;    // next-step controller input
    }
    __syncthreads();                                               // 12

    // ---- output GEMV (coalesced): cr[320] @ Wf[320][64]
    // thread (ip=tid>>3 covers 5 i, jc=tid&7 covers 8 j)
    {
      const int jc = tid & 7, ip = tid >> 3;
      const int i0 = ip * 5;
      float acc[8] = {0.f, 0.f, 0.f, 0.f, 0.f, 0.f, 0.f, 0.f};
      #pragma unroll
      for (int u = 0; u < 5; ++u) {
        float f[8]; ld8(Wf + (i0 + u) * kOUT + jc * 8, f);
        float cv = sm.cr[i0 + u];
        #pragma unroll
        for (int v = 0; v < 8; ++v) acc[v] = fmaf(cv, f[v], acc[v]);
      }
      #pragma unroll
      for (int v = 0; v < 8; ++v) {
        acc[v] += __shfl_xor(acc[v], 8);
        acc[v] += __shfl_xor(acc[v], 16);
        acc[v] += __shfl_xor(acc[v], 32);
      }
      if ((lane & 56) == 0) {   // lanes 0..7
        *(float4*)&sm.partA[wid * 64 + jc * 8]     = make_float4(acc[0], acc[1], acc[2], acc[3]);
        *(float4*)&sm.partA[wid * 64 + jc * 8 + 4] = make_float4(acc[4], acc[5], acc[6], acc[7]);
      }
    }
    __syncthreads();                                               // 13
    if (tid < kOUT) {
      float s = sm.bfS[tid];
      #pragma unroll
      for (int w = 0; w < NW; ++w) s += sm.partA[w * 64 + tid];
      stf(out, (b * kT + t) * kOUT + tid, sigmoidf_(s));
    } else if (tid >= 64 && tid < 72 && t + 1 < kT) {
      // stage next step's x_t (coalesced 16B loads by 8 threads)
      int t8 = tid - 64;
      float f[8]; ld8(x + ((size_t)b * kT + (t + 1)) * kIN + t8 * 8, f);
      #pragma unroll
      for (int u = 0; u < 8; ++u) sm.in[t8 * 8 + u] = f[u];
    }
    __syncthreads();                                               // 14
  }
}

template <typename TD, int WANT, int PACKED>
static void launch_variant(void* const* d_in, void* d_out, const int* flag,
                           const void* pk, hipStream_t stream) {
  ntm_fused<TD, WANT, PACKED><<<dim3(kB), dim3(NT), 0, stream>>>(
      (const TD*)d_in[0], (const TD*)d_in[1], (const TD*)d_in[2],
      (const TD*)d_in[3], (const TD*)d_in[4], (const TD*)d_in[5],
      (const TD*)d_in[6], (const TD*)d_in[7], (const TD*)d_in[8],
      (const TD*)d_in[9], (const TD*)d_in[10], (const TD*)d_in[11],
      (const TD*)pk, (TD*)d_out, flag);
}

extern "C" void kernel_launch(void* const* d_in, const int* in_sizes, int n_in,
                              void* d_out, int out_size, void* d_ws, size_t ws_size,
                              hipStream_t stream) {
  (void)in_sizes; (void)n_in; (void)out_size;
  int* flag = (int*)d_ws;
  detect_dtype<<<dim3(1), dim3(64), 0, stream>>>(d_in[10], flag);
  if (ws_size >= kWsNeeded) {
    void* pk = (void*)((char*)d_ws + 256);
    repack_w<__hip_bfloat16, 1><<<dim3(256), dim3(256), 0, stream>>>(
        (const __hip_bfloat16*)d_in[5], (const __hip_bfloat16*)d_in[3],
        (__hip_bfloat16*)pk, flag);
    repack_w<float, 0><<<dim3(256), dim3(256), 0, stream>>>(
        (const float*)d_in[5], (const float*)d_in[3],
        (float*)pk, flag);
    launch_variant<__hip_bfloat16, 1, 1>(d_in, d_out, flag, pk, stream);
    launch_variant<float, 0, 1>(d_in, d_out, flag, pk, stream);
  } else {
    launch_variant<__hip_bfloat16, 1, 0>(d_in, d_out, flag, nullptr, stream);
    launch_variant<float, 0, 0>(d_in, d_out, flag, nullptr, stream);
  }
}

// Round 9
// 1366.879 us; speedup vs baseline: 1.1552x; 1.1552x over previous
//
#include <hip/hip_runtime.h>
#include <hip/hip_bf16.h>
#include <math.h>

// NTM forward, fully fused: one block per batch element, T=64 steps in-kernel.
// Rev 9b: identical design to Rev 9 (round-8 submission, which failed on an
// infra container error before producing any measurement). Resubmitted to get
// the skeleton-reduction theory measured.
// Design: attack the serial skeleton, not the phases.
// Evidence rounds 1-7: spill volume, load coalescing, M residency all varied
// by large factors; dur stayed 1466-1748us. Constant: 14 barrier-delimited
// segments/step = ~4.5k cycles each of serialized dependency latency.
// Changes (skeleton 14 -> 9 segments):
//  - cpre kernel precomputes bc + x_t@Wc_x for ALL (b,t) on all 256 CUs;
//    controller becomes a 64-input dot (r-part only).
//  - full-dot GEMVs (1 output/thread): no partial-reduce barriers.
//  - output FC split: c-part partials in the params segment (idle waves 4-7),
//    r-part + store overlapped with NEXT step's controller segment.
//  - addressing drops softmax max-subtract (mathematically identical
//    normalization; sim = beta*cos <= ~5, guarded by min(.,80)):
//    2 barriers per address instead of 3; head scalars recomputed per-thread
//    from LDS broadcasts.
// M stays hierarchical (reg row + LDS row, round-6 layout: 0 conflicts, no
// spill at the 128-VGPR grant). NT=512.

constexpr int kB  = 64;
constexpr int kT  = 64;
constexpr int kIN = 64;
constexpr int kC  = 256;
constexpr int kN  = 1024;
constexpr int kMV = 64;
constexpr int kOUT = 64;
constexpr int kHW = 198;   // write head raw dim: MV+6+2*MV
constexpr int kHR = 70;    // read head raw dim: MV+6
constexpr int NT  = 512;   // threads per block (8 waves)
constexpr int NW  = NT / 64;
constexpr float kEPS = 1e-8f;

// packed (transposed) weight layout, offsets in elements
constexpr int kPWc = 0;                          // WcT [256][128]
constexpr int kPWw = kPWc + kC * 128;            // WwT [198][256] @ 32768
constexpr int kPWr = kPWw + kHW * kC;            // WrT [70][256]  @ 83456
constexpr int kPWf = kPWr + kHR * kC;            // WfT [64][320]  @ 101376
constexpr int kPTotal = kPWf + kOUT * (kC + kMV);  // 121856 elements
constexpr size_t kWsPack = 256 + (size_t)kPTotal * 4;            // ~487KB
constexpr int kCpreElems = kB * kT * kC;                          // 1M floats
constexpr size_t kWsFull = kWsPack + (size_t)kCpreElems * 4;      // ~4.7MB

__device__ __forceinline__ float ldf(const float* p, int i) { return p[i]; }
__device__ __forceinline__ float ldf(const __hip_bfloat16* p, int i) { return __bfloat162float(p[i]); }
__device__ __forceinline__ void stf(float* p, int i, float v) { p[i] = v; }
__device__ __forceinline__ void stf(__hip_bfloat16* p, int i, float v) { p[i] = __float2bfloat16(v); }

// 8 contiguous elements -> float[8]; 16B-aligned by construction.
__device__ __forceinline__ void ld8(const __hip_bfloat16* p, float* f) {
  uint4 u = *reinterpret_cast<const uint4*>(p);
  f[0] = __uint_as_float(u.x << 16); f[1] = __uint_as_float(u.x & 0xffff0000u);
  f[2] = __uint_as_float(u.y << 16); f[3] = __uint_as_float(u.y & 0xffff0000u);
  f[4] = __uint_as_float(u.z << 16); f[5] = __uint_as_float(u.z & 0xffff0000u);
  f[6] = __uint_as_float(u.w << 16); f[7] = __uint_as_float(u.w & 0xffff0000u);
}
__device__ __forceinline__ void ld8(const float* p, float* f) {
  float4 a = reinterpret_cast<const float4*>(p)[0];
  float4 b = reinterpret_cast<const float4*>(p)[1];
  f[0] = a.x; f[1] = a.y; f[2] = a.z; f[3] = a.w;
  f[4] = b.x; f[5] = b.y; f[6] = b.z; f[7] = b.w;
}

__device__ __forceinline__ float fexp(float v) { return __expf(v); }
__device__ __forceinline__ float sigmoidf_(float v) {
  return __fdividef(1.f, 1.f + __expf(-v));
}
__device__ __forceinline__ float softplusf_(float v) {
  return v > 20.f ? v : __logf(1.f + __expf(v));
}
__device__ __forceinline__ float ftanh(float v) {
  float a = fminf(fabsf(v), 15.f);          // tanh(15) == 1 in fp32
  float e = __expf(2.f * a);
  float t = 1.f - __fdividef(2.f, e + 1.f);
  return v < 0.f ? -t : t;
}

__device__ __forceinline__ float wsum(float v) {
  v += __shfl_xor(v, 32); v += __shfl_xor(v, 16); v += __shfl_xor(v, 8);
  v += __shfl_xor(v, 4);  v += __shfl_xor(v, 2);  v += __shfl_xor(v, 1);
  return v;
}

struct alignas(16) Smem {
  // M rows 512..1023: [block b=col/4][row r][4 floats]; lane-contiguous b128.
  float M1s[16 * 512 * 4];   // 128 KB
  float partA[1280];         // [0..268) head dots | [512..768) outc partials
                             // | [768..1280) butterfly wave partials
  float E[kN];               // unnormalized content softmax numerators
  float WP[kN];              // previous weights (for shift conv)
  float c[kC];               // controller activations
  float r[kMV];              // read vector
  float k[kMV], kr[kMV], e[kMV], a[kMV];
  float bcS[kC], bwS[kHW], brS[kHR], bfS[kOUT];   // biases (staged once)
  float red[2][NW];          // cross-wave reduction slots
  float scal[16];            // 6: |k| write, 14: |k| read
};
static_assert(sizeof(Smem) <= 160 * 1024, "LDS budget");

__device__ __forceinline__ int m1idx(int blk, int row) { return (blk * 512 + row) * 4; }

// flag: 1 if buffers are bf16, 0 if fp32.  w_bias is a softmax -> sums to 1.
__global__ void detect_dtype(const void* wb, int* flag) {
  const unsigned short* u = (const unsigned short*)wb;
  int lane = threadIdx.x;
  float s = 0.f;
  for (int i = lane; i < kN; i += 64)
    s += __uint_as_float(((unsigned int)u[i]) << 16);
  s = wsum(s);
  if (lane == 0 && blockIdx.x == 0)
    *flag = (s > 0.75f && s < 1.25f) ? 1 : 0;
}

// Transpose-repack the four weight matrices into workspace (coalesced writes).
template <typename TD, int WANT>
__global__ void repack_w(const TD* __restrict__ Wc, const TD* __restrict__ Ww,
                         const TD* __restrict__ Wr, const TD* __restrict__ Wf,
                         TD* __restrict__ pk, const int* __restrict__ flag) {
  if (*flag != WANT) return;
  for (int idx = blockIdx.x * blockDim.x + threadIdx.x; idx < kPTotal;
       idx += gridDim.x * blockDim.x) {
    TD v;
    if (idx < kPWw) {                       // WcT[j][i] = Wc[i][j], [128][256] src
      int r = idx, j = r >> 7, i = r & 127;
      v = Wc[i * kC + j];
    } else if (idx < kPWr) {                // WwT[j][i] = Ww[i][j], [256][198] src
      int r = idx - kPWw, j = r >> 8, i = r & 255;
      v = Ww[i * kHW + j];
    } else if (idx < kPWf) {                // WrT[j][i] = Wr[i][j], [256][70] src
      int r = idx - kPWr, j = r >> 8, i = r & 255;
      v = Wr[i * kHR + j];
    } else {                                // WfT[j][i] = Wf[i][j], [320][64] src
      int r = idx - kPWf, j = r / 320, i = r % 320;
      v = Wf[i * kOUT + j];
    }
    pk[idx] = v;
  }
}

// cpre[b][t][j] = bc[j] + sum_{i<64} x[b][t][i] * Wc[i][j].
// Grid = B*T blocks of 256 threads: uses the whole GPU.
template <typename TD, int WANT>
__global__ void cpre_kernel(const TD* __restrict__ x, const TD* __restrict__ bc,
                            const TD* __restrict__ pk, float* __restrict__ cpre,
                            const int* __restrict__ flag) {
  if (*flag != WANT) return;
  const int bt = blockIdx.x;              // 0..B*T-1
  const int tid = threadIdx.x;            // output j
  __shared__ float xs[kIN];
  if (tid < kIN) xs[tid] = ldf(x, (size_t)bt * kIN + tid);
  __syncthreads();
  const TD* row = pk + kPWc + tid * 128;  // WcT row j, x-part cols 0..63
  float s = ldf(bc, tid);
  #pragma unroll
  for (int q = 0; q < 8; ++q) {
    float f[8]; ld8(row + 8 * q, f);
    #pragma unroll
    for (int u = 0; u < 8; ++u) s = fmaf(xs[8 * q + u], f[u], s);
  }
  cpre[(size_t)bt * kC + tid] = s;
}

// MODE: 2 = packed + cpre, 1 = packed (x-part inline), 0 = direct strided.
template <typename TD, int WANT, int MODE>
__global__ __launch_bounds__(NT, 1) void ntm_fused(
    const TD* __restrict__ x,
    const TD* __restrict__ Wc, const TD* __restrict__ bc,
    const TD* __restrict__ Wr, const TD* __restrict__ br,
    const TD* __restrict__ Ww, const TD* __restrict__ bw,
    const TD* __restrict__ Wf, const TD* __restrict__ bf,
    const TD* __restrict__ r_bias, const TD* __restrict__ w_bias,
    const TD* __restrict__ M_bias,
    const TD* __restrict__ pk, const float* __restrict__ cpre,
    TD* __restrict__ out, const int* __restrict__ flag) {
  if (*flag != WANT) return;
  __shared__ Smem sm;
  const int tid  = threadIdx.x;
  const int b    = blockIdx.x;
  const int lane = tid & 63;
  const int wid  = tid >> 6;

  // ---- one-time staging: biases, r_bias
  if (tid < kC)  sm.bcS[tid] = ldf(bc, tid);
  if (tid < kHW) sm.bwS[tid] = ldf(bw, tid);
  if (tid < kHR) sm.brS[tid] = ldf(br, tid);
  if (tid < kOUT) sm.bfS[tid] = ldf(bf, tid);
  if (tid < kMV) sm.r[tid] = ldf(r_bias, tid);

  // ---- init state: reg row (tid) + LDS row (tid+512), norms, prev weights
  float M0[kMV];
  float n2_0 = 0.f, n2_1 = 0.f;
  #pragma unroll
  for (int jb = 0; jb < kMV; jb += 8) {
    float f0[8], f1[8];
    ld8(M_bias + (size_t)tid * kMV + jb, f0);
    ld8(M_bias + (size_t)(tid + NT) * kMV + jb, f1);
    #pragma unroll
    for (int u = 0; u < 8; ++u) {
      M0[jb + u] = f0[u];
      n2_0 = fmaf(f0[u], f0[u], n2_0);
      n2_1 = fmaf(f1[u], f1[u], n2_1);
    }
    *(float4*)&sm.M1s[m1idx(jb >> 2, tid)] = make_float4(f1[0], f1[1], f1[2], f1[3]);
    *(float4*)&sm.M1s[m1idx((jb >> 2) + 1, tid)] = make_float4(f1[4], f1[5], f1[6], f1[7]);
  }
  float wp0 = ldf(w_bias, tid);
  float wp1 = ldf(w_bias, tid + NT);
  __syncthreads();

  #pragma unroll 1
  for (int t = 0; t < kT; ++t) {
    // ==== SEG 1: controller full-dot (threads 0..255)  ||  out store for
    //     step t-1 (threads 256..319).  Both depend only on r_{t-1}.
    if (tid < kC) {
      float s;
      if constexpr (MODE == 2) {
        s = cpre[((size_t)b * kT + t) * kC + tid];   // bc + x-part
      } else if constexpr (MODE == 1) {
        s = sm.bcS[tid];
        const TD* xrow = x + ((size_t)b * kT + t) * kIN;
        const TD* row = pk + kPWc + tid * 128;       // x-part cols 0..63
        #pragma unroll
        for (int q = 0; q < 8; ++q) {
          float f[8], xv[8];
          ld8(row + 8 * q, f); ld8(xrow + 8 * q, xv);
          #pragma unroll
          for (int u = 0; u < 8; ++u) s = fmaf(xv[u], f[u], s);
        }
      } else {
        s = sm.bcS[tid];
        for (int i = 0; i < kIN; ++i)
          s = fmaf(ldf(x, ((size_t)b * kT + t) * kIN + i), ldf(Wc, i * kC + tid), s);
      }
      // r-part
      if constexpr (MODE >= 1) {
        const TD* row = pk + kPWc + tid * 128 + 64;  // cols 64..127 contiguous
        #pragma unroll
        for (int q = 0; q < 8; ++q) {
          float f[8]; ld8(row + 8 * q, f);
          float4 ra = *(const float4*)&sm.r[8 * q];
          float4 rb = *(const float4*)&sm.r[8 * q + 4];
          s = fmaf(ra.x, f[0], s); s = fmaf(ra.y, f[1], s);
          s = fmaf(ra.z, f[2], s); s = fmaf(ra.w, f[3], s);
          s = fmaf(rb.x, f[4], s); s = fmaf(rb.y, f[5], s);
          s = fmaf(rb.z, f[6], s); s = fmaf(rb.w, f[7], s);
        }
      } else {
        for (int i = 0; i < kMV; ++i)
          s = fmaf(sm.r[i], ldf(Wc, (kIN + i) * kC + tid), s);
      }
      sm.c[tid] = ftanh(s);
    } else if (tid < 320 && t > 0) {
      const int j = tid - 256;
      float s = sm.bfS[j] + sm.partA[512 + j] + sm.partA[576 + j] +
                sm.partA[640 + j] + sm.partA[704 + j];
      if constexpr (MODE >= 1) {
        const TD* row = pk + kPWf + j * (kC + kMV) + kC;  // r-part cols 256..319
        #pragma unroll
        for (int q = 0; q < 8; ++q) {
          float f[8]; ld8(row + 8 * q, f);
          float4 ra = *(const float4*)&sm.r[8 * q];
          float4 rb = *(const float4*)&sm.r[8 * q + 4];
          s = fmaf(ra.x, f[0], s); s = fmaf(ra.y, f[1], s);
          s = fmaf(ra.z, f[2], s); s = fmaf(ra.w, f[3], s);
          s = fmaf(rb.x, f[4], s); s = fmaf(rb.y, f[5], s);
          s = fmaf(rb.z, f[6], s); s = fmaf(rb.w, f[7], s);
        }
      } else {
        for (int i = 0; i < kMV; ++i)
          s = fmaf(sm.r[i], ldf(Wf, (kC + i) * kOUT + j), s);
      }
      stf(out, ((size_t)b * kT + (t - 1)) * kOUT + j, sigmoidf_(s));
    }
    __syncthreads();                                               // B1

    // ==== SEG 2: head full-dots (threads 0..267): hw[tid] or hr[tid-198]
    if (tid < kHW + kHR) {
      float a0 = 0.f, a1 = 0.f, a2 = 0.f, a3 = 0.f;
      if constexpr (MODE >= 1) {
        const TD* row = (tid < kHW) ? (pk + kPWw + tid * kC)
                                    : (pk + kPWr + (tid - kHW) * kC);
        #pragma unroll 8
        for (int q = 0; q < 32; ++q) {
          float f[8]; ld8(row + 8 * q, f);
          float4 ca = *(const float4*)&sm.c[8 * q];
          float4 cb = *(const float4*)&sm.c[8 * q + 4];
          a0 = fmaf(ca.x, f[0], a0); a1 = fmaf(ca.y, f[1], a1);
          a2 = fmaf(ca.z, f[2], a2); a3 = fmaf(ca.w, f[3], a3);
          a0 = fmaf(cb.x, f[4], a0); a1 = fmaf(cb.y, f[5], a1);
          a2 = fmaf(cb.z, f[6], a2); a3 = fmaf(cb.w, f[7], a3);
        }
      } else {
        for (int i = 0; i < kC; ++i) {
          float wv = (tid < kHW) ? ldf(Ww, i * kHW + tid)
                                 : ldf(Wr, i * kHR + (tid - kHW));
          a0 = fmaf(sm.c[i], wv, a0);
        }
      }
      sm.partA[tid] = (a0 + a1) + (a2 + a3);
    }
    __syncthreads();                                               // B2

    // ==== SEG 3: head vector params (waves 0..3)  ||  out c-part partials
    //     (threads 256..511: 64 outs x 4 partials of 64 c-inputs)
    if (wid == 0) {                       // write key + |k|
      float kv = ftanh(sm.partA[lane] + sm.bwS[lane]);
      sm.k[lane] = kv;
      float s = wsum(kv * kv);
      if (lane == 0) sm.scal[6] = sqrtf(s);
    } else if (wid == 1) {                // erase
      sm.e[lane] = sigmoidf_(sm.partA[70 + lane] + sm.bwS[70 + lane]);
    } else if (wid == 2) {                // add
      sm.a[lane] = ftanh(sm.partA[134 + lane] + sm.bwS[134 + lane]);
    } else if (wid == 3) {                // read key + |k|
      float kv = ftanh(sm.partA[kHW + lane] + sm.brS[lane]);
      sm.kr[lane] = kv;
      float s = wsum(kv * kv);
      if (lane == 0) sm.scal[14] = sqrtf(s);
    } else {                              // threads 256..511: outc partials
      const int j = (tid - 256) & 63, po = (tid - 256) >> 6;
      float s = 0.f;
      if constexpr (MODE >= 1) {
        const TD* row = pk + kPWf + j * (kC + kMV) + po * 64;
        #pragma unroll
        for (int q = 0; q < 8; ++q) {
          float f[8]; ld8(row + 8 * q, f);
          float4 ca = *(const float4*)&sm.c[po * 64 + 8 * q];
          float4 cb = *(const float4*)&sm.c[po * 64 + 8 * q + 4];
          s = fmaf(ca.x, f[0], s); s = fmaf(ca.y, f[1], s);
          s = fmaf(ca.z, f[2], s); s = fmaf(ca.w, f[3], s);
          s = fmaf(cb.x, f[4], s); s = fmaf(cb.y, f[5], s);
          s = fmaf(cb.z, f[6], s); s = fmaf(cb.w, f[7], s);
        }
      } else {
        for (int i = 0; i < 64; ++i)
          s = fmaf(sm.c[po * 64 + i], ldf(Wf, (po * 64 + i) * kOUT + j), s);
      }
      sm.partA[512 + po * 64 + j] = s;
    }
    __syncthreads();                                               // B3

    // ==== SEG 4: write-head addressing, part 1 (dots + exp + block sum)
    float ww0, ww1, gW, s0W, s1W, s2W, gammaW;
    float e0W, e1W, p0W, p1W;
    {
      // head scalars, redundantly per-thread (broadcast LDS reads)
      float beta = softplusf_(sm.partA[64] + sm.bwS[64]);
      gW = sigmoidf_(sm.partA[65] + sm.bwS[65]);
      gammaW = 1.f + softplusf_(sm.partA[69] + sm.bwS[69]);
      float a0 = sm.partA[66] + sm.bwS[66];
      float a1 = sm.partA[67] + sm.bwS[67];
      float a2 = sm.partA[68] + sm.bwS[68];
      float mx = fmaxf(a0, fmaxf(a1, a2));
      float ex0 = fexp(a0 - mx), ex1 = fexp(a1 - mx), ex2 = fexp(a2 - mx);
      float dd = __fdividef(1.f, ex0 + ex1 + ex2);
      s0W = ex0 * dd; s1W = ex1 * dd; s2W = ex2 * dd;
      float kn = sm.scal[6];
      float d0 = 0.f, d1 = 0.f;
      #pragma unroll
      for (int bq = 0; bq < 16; ++bq) {
        float4 kv = *(const float4*)&sm.k[bq * 4];
        d0 = fmaf(M0[bq * 4],     kv.x, d0);
        d0 = fmaf(M0[bq * 4 + 1], kv.y, d0);
        d0 = fmaf(M0[bq * 4 + 2], kv.z, d0);
        d0 = fmaf(M0[bq * 4 + 3], kv.w, d0);
        float4 mv = *(const float4*)&sm.M1s[m1idx(bq, tid)];
        d1 = fmaf(mv.x, kv.x, d1); d1 = fmaf(mv.y, kv.y, d1);
        d1 = fmaf(mv.z, kv.z, d1); d1 = fmaf(mv.w, kv.w, d1);
      }
      float sim0 = fminf(beta * d0 / (sqrtf(n2_0) * kn + kEPS), 80.f);
      float sim1 = fminf(beta * d1 / (sqrtf(n2_1) * kn + kEPS), 80.f);
      e0W = fexp(sim0); e1W = fexp(sim1);
      sm.E[tid] = e0W; sm.E[tid + NT] = e1W;
      sm.WP[tid] = wp0; sm.WP[tid + NT] = wp1;
      float sv = wsum(e0W + e1W);
      if (lane == 0) sm.red[0][wid] = sv;
    }
    __syncthreads();                                               // B4

    // ==== SEG 5: write-head addressing, part 2 (norm + shift + sharpen)
    {
      float gsum = 0.f;
      #pragma unroll
      for (int i = 0; i < NW; ++i) gsum += sm.red[0][i];
      float inv = __fdividef(1.f, gsum);
      float wg0 = fmaf(gW, fmaf(e0W, inv, -wp0), wp0);
      float wg1 = fmaf(gW, fmaf(e1W, inv, -wp1), wp1);
      int np = (tid + 1) & (kN - 1), nm = (tid + kN - 1) & (kN - 1);
      float wgp = fmaf(gW, fmaf(sm.E[np], inv, -sm.WP[np]), sm.WP[np]);
      float wgm = fmaf(gW, fmaf(sm.E[nm], inv, -sm.WP[nm]), sm.WP[nm]);
      float ws0 = s0W * wgp + s1W * wg0 + s2W * wgm;
      int npb = (tid + NT + 1) & (kN - 1), nmb = (tid + NT - 1) & (kN - 1);
      float wgpb = fmaf(gW, fmaf(sm.E[npb], inv, -sm.WP[npb]), sm.WP[npb]);
      float wgmb = fmaf(gW, fmaf(sm.E[nmb], inv, -sm.WP[nmb]), sm.WP[nmb]);
      float ws1 = s0W * wgpb + s1W * wg1 + s2W * wgmb;
      p0W = fexp(gammaW * __logf(ws0 + kEPS));
      p1W = fexp(gammaW * __logf(ws1 + kEPS));
      float pv = wsum(p0W + p1W);
      if (lane == 0) sm.red[1][wid] = pv;
    }
    __syncthreads();                                               // B5
    {
      float psum = 0.f;
      #pragma unroll
      for (int i = 0; i < NW; ++i) psum += sm.red[1][i];
      float ipn = __fdividef(1.f, psum);
      ww0 = p0W * ipn; ww1 = p1W * ipn;
    }

    // ==== SEG 6: memory update (+ read dot + norms) + read-head part 1
    float wr0, wr1, gR, s0R, s1R, s2R, gammaR;
    float e0R, e1R, p0R, p1R;
    float dr0 = 0.f, dr1 = 0.f, nn0 = 0.f, nn1 = 0.f;
    {
      #pragma unroll
      for (int bq = 0; bq < 16; ++bq) {
        float4 ev = *(const float4*)&sm.e[bq * 4];
        float4 av = *(const float4*)&sm.a[bq * 4];
        float4 kv = *(const float4*)&sm.kr[bq * 4];
        {
          float m = fmaf(ww0, fmaf(-ev.x, M0[bq * 4], av.x), M0[bq * 4]);
          M0[bq * 4] = m; dr0 = fmaf(m, kv.x, dr0); nn0 = fmaf(m, m, nn0);
        }
        {
          float m = fmaf(ww0, fmaf(-ev.y, M0[bq * 4 + 1], av.y), M0[bq * 4 + 1]);
          M0[bq * 4 + 1] = m; dr0 = fmaf(m, kv.y, dr0); nn0 = fmaf(m, m, nn0);
        }
        {
          float m = fmaf(ww0, fmaf(-ev.z, M0[bq * 4 + 2], av.z), M0[bq * 4 + 2]);
          M0[bq * 4 + 2] = m; dr0 = fmaf(m, kv.z, dr0); nn0 = fmaf(m, m, nn0);
        }
        {
          float m = fmaf(ww0, fmaf(-ev.w, M0[bq * 4 + 3], av.w), M0[bq * 4 + 3]);
          M0[bq * 4 + 3] = m; dr0 = fmaf(m, kv.w, dr0); nn0 = fmaf(m, m, nn0);
        }
        int fi = m1idx(bq, tid);
        float4 mv = *(const float4*)&sm.M1s[fi];
        float4 nm;
        nm.x = fmaf(ww1, fmaf(-ev.x, mv.x, av.x), mv.x);
        dr1 = fmaf(nm.x, kv.x, dr1); nn1 = fmaf(nm.x, nm.x, nn1);
        nm.y = fmaf(ww1, fmaf(-ev.y, mv.y, av.y), mv.y);
        dr1 = fmaf(nm.y, kv.y, dr1); nn1 = fmaf(nm.y, nm.y, nn1);
        nm.z = fmaf(ww1, fmaf(-ev.z, mv.z, av.z), mv.z);
        dr1 = fmaf(nm.z, kv.z, dr1); nn1 = fmaf(nm.z, nm.z, nn1);
        nm.w = fmaf(ww1, fmaf(-ev.w, mv.w, av.w), mv.w);
        dr1 = fmaf(nm.w, kv.w, dr1); nn1 = fmaf(nm.w, nm.w, nn1);
        *(float4*)&sm.M1s[fi] = nm;
      }
      // read-head scalars, redundant per-thread
      float beta = softplusf_(sm.partA[kHW + 64] + sm.brS[64]);
      gR = sigmoidf_(sm.partA[kHW + 65] + sm.brS[65]);
      gammaR = 1.f + softplusf_(sm.partA[kHW + 69] + sm.brS[69]);
      float a0 = sm.partA[kHW + 66] + sm.brS[66];
      float a1 = sm.partA[kHW + 67] + sm.brS[67];
      float a2 = sm.partA[kHW + 68] + sm.brS[68];
      float mx = fmaxf(a0, fmaxf(a1, a2));
      float ex0 = fexp(a0 - mx), ex1 = fexp(a1 - mx), ex2 = fexp(a2 - mx);
      float dd = __fdividef(1.f, ex0 + ex1 + ex2);
      s0R = ex0 * dd; s1R = ex1 * dd; s2R = ex2 * dd;
      float kn = sm.scal[14];
      float sim0 = fminf(beta * dr0 / (sqrtf(nn0) * kn + kEPS), 80.f);
      float sim1 = fminf(beta * dr1 / (sqrtf(nn1) * kn + kEPS), 80.f);
      e0R = fexp(sim0); e1R = fexp(sim1);
      sm.E[tid] = e0R; sm.E[tid + NT] = e1R;
      sm.WP[tid] = ww0; sm.WP[tid + NT] = ww1;
      float sv = wsum(e0R + e1R);
      if (lane == 0) sm.red[0][wid] = sv;
    }
    __syncthreads();                                               // B6

    // ==== SEG 7: read-head addressing, part 2
    {
      float gsum = 0.f;
      #pragma unroll
      for (int i = 0; i < NW; ++i) gsum += sm.red[0][i];
      float inv = __fdividef(1.f, gsum);
      float wg0 = fmaf(gR, fmaf(e0R, inv, -ww0), ww0);
      float wg1 = fmaf(gR, fmaf(e1R, inv, -ww1), ww1);
      int np = (tid + 1) & (kN - 1), nm = (tid + kN - 1) & (kN - 1);
      float wgp = fmaf(gR, fmaf(sm.E[np], inv, -sm.WP[np]), sm.WP[np]);
      float wgm = fmaf(gR, fmaf(sm.E[nm], inv, -sm.WP[nm]), sm.WP[nm]);
      float ws0 = s0R * wgp + s1R * wg0 + s2R * wgm;
      int npb = (tid + NT + 1) & (kN - 1), nmb = (tid + NT - 1) & (kN - 1);
      float wgpb = fmaf(gR, fmaf(sm.E[npb], inv, -sm.WP[npb]), sm.WP[npb]);
      float wgmb = fmaf(gR, fmaf(sm.E[nmb], inv, -sm.WP[nmb]), sm.WP[nmb]);
      float ws1 = s0R * wgpb + s1R * wg1 + s2R * wgmb;
      p0R = fexp(gammaR * __logf(ws0 + kEPS));
      p1R = fexp(gammaR * __logf(ws1 + kEPS));
      float pv = wsum(p0R + p1R);
      if (lane == 0) sm.red[1][wid] = pv;
    }
    __syncthreads();                                               // B7
    {
      float psum = 0.f;
      #pragma unroll
      for (int i = 0; i < NW; ++i) psum += sm.red[1][i];
      float ipn = __fdividef(1.f, psum);
      wr0 = p0R * ipn; wr1 = p1R * ipn;
    }
    wp0 = wr0; wp1 = wr1; n2_0 = nn0; n2_1 = nn1;   // carry state

    // ==== SEG 8: read vector butterfly partials (round-6 two-pass)
    {
      {
        float cur[16];
        const int b0 = lane & 1;
        #pragma unroll
        for (int qq = 0; qq < 8; ++qq) {
          float4 mv = *(const float4*)&sm.M1s[m1idx(qq, tid)];
          float v0 = fmaf(wr0, M0[4 * qq],     wr1 * mv.x);
          float v1 = fmaf(wr0, M0[4 * qq + 1], wr1 * mv.y);
          float keep = b0 ? v1 : v0, send = b0 ? v0 : v1;
          cur[2 * qq] = keep + __shfl_xor(send, 1);
          float v2 = fmaf(wr0, M0[4 * qq + 2], wr1 * mv.z);
          float v3 = fmaf(wr0, M0[4 * qq + 3], wr1 * mv.w);
          keep = b0 ? v3 : v2; send = b0 ? v2 : v3;
          cur[2 * qq + 1] = keep + __shfl_xor(send, 1);
        }
        #pragma unroll
        for (int st = 1; st < 5; ++st) {
          const int d = 1 << st;
          const int bb = (lane >> st) & 1;
          #pragma unroll
          for (int q = 0; q < (16 >> st); ++q) {
            float x0 = cur[2 * q], x1 = cur[2 * q + 1];
            float keep = bb ? x1 : x0, send = bb ? x0 : x1;
            cur[q] = keep + __shfl_xor(send, d);
          }
        }
        float tot = cur[0] + __shfl_xor(cur[0], 32);
        if (lane < 32) sm.partA[768 + wid * 64 + lane] = tot;
      }
      {
        float cur[16];
        const int b0 = lane & 1;
        #pragma unroll
        for (int qq = 0; qq < 8; ++qq) {
          float4 mv = *(const float4*)&sm.M1s[m1idx(8 + qq, tid)];
          float v0 = fmaf(wr0, M0[32 + 4 * qq],     wr1 * mv.x);
          float v1 = fmaf(wr0, M0[32 + 4 * qq + 1], wr1 * mv.y);
          float keep = b0 ? v1 : v0, send = b0 ? v0 : v1;
          cur[2 * qq] = keep + __shfl_xor(send, 1);
          float v2 = fmaf(wr0, M0[32 + 4 * qq + 2], wr1 * mv.z);
          float v3 = fmaf(wr0, M0[32 + 4 * qq + 3], wr1 * mv.w);
          keep = b0 ? v3 : v2; send = b0 ? v2 : v3;
          cur[2 * qq + 1] = keep + __shfl_xor(send, 1);
        }
        #pragma unroll
        for (int st = 1; st < 5; ++st) {
          const int d = 1 << st;
          const int bb = (lane >> st) & 1;
          #pragma unroll
          for (int q = 0; q < (16 >> st); ++q) {
            float x0 = cur[2 * q], x1 = cur[2 * q + 1];
            float keep = bb ? x1 : x0, send = bb ? x0 : x1;
            cur[q] = keep + __shfl_xor(send, d);
          }
        }
        float tot = cur[0] + __shfl_xor(cur[0], 32);
        if (lane < 32) sm.partA[768 + wid * 64 + 32 + lane] = tot;
      }
    }
    __syncthreads();                                               // B8

    // ==== SEG 9: r reduce (threads 0..63)
    if (tid < kMV) {
      float s = sm.partA[768 + tid];
      #pragma unroll
      for (int w = 1; w < NW; ++w) s += sm.partA[768 + w * 64 + tid];
      sm.r[tid] = s;
    }
    __syncthreads();                                               // B9
  }

  // ==== epilogue: output for t = kT-1 (outc partials + r are intact)
  if (tid >= 256 && tid < 320) {
    const int j = tid - 256;
    float s = sm.bfS[j] + sm.partA[512 + j] + sm.partA[576 + j] +
              sm.partA[640 + j] + sm.partA[704 + j];
    if constexpr (MODE >= 1) {
      const TD* row = pk + kPWf + j * (kC + kMV) + kC;
      #pragma unroll
      for (int q = 0; q < 8; ++q) {
        float f[8]; ld8(row + 8 * q, f);
        float4 ra = *(const float4*)&sm.r[8 * q];
        float4 rb = *(const float4*)&sm.r[8 * q + 4];
        s = fmaf(ra.x, f[0], s); s = fmaf(ra.y, f[1], s);
        s = fmaf(ra.z, f[2], s); s = fmaf(ra.w, f[3], s);
        s = fmaf(rb.x, f[4], s); s = fmaf(rb.y, f[5], s);
        s = fmaf(rb.z, f[6], s); s = fmaf(rb.w, f[7], s);
      }
    } else {
      for (int i = 0; i < kMV; ++i)
        s = fmaf(sm.r[i], ldf(Wf, (kC + i) * kOUT + j), s);
    }
    stf(out, ((size_t)b * kT + (kT - 1)) * kOUT + j, sigmoidf_(s));
  }
}

template <typename TD, int WANT, int MODE>
static void launch_variant(void* const* d_in, void* d_out, const int* flag,
                           const void* pk, const float* cpre, hipStream_t stream) {
  ntm_fused<TD, WANT, MODE><<<dim3(kB), dim3(NT), 0, stream>>>(
      (const TD*)d_in[0], (const TD*)d_in[1], (const TD*)d_in[2],
      (const TD*)d_in[3], (const TD*)d_in[4], (const TD*)d_in[5],
      (const TD*)d_in[6], (const TD*)d_in[7], (const TD*)d_in[8],
      (const TD*)d_in[9], (const TD*)d_in[10], (const TD*)d_in[11],
      (const TD*)pk, cpre, (TD*)d_out, flag);
}

extern "C" void kernel_launch(void* const* d_in, const int* in_sizes, int n_in,
                              void* d_out, int out_size, void* d_ws, size_t ws_size,
                              hipStream_t stream) {
  (void)in_sizes; (void)n_in; (void)out_size;
  int* flag = (int*)d_ws;
  detect_dtype<<<dim3(1), dim3(64), 0, stream>>>(d_in[10], flag);
  if (ws_size >= kWsPack) {
    void* pk = (void*)((char*)d_ws + 256);
    repack_w<__hip_bfloat16, 1><<<dim3(256), dim3(256), 0, stream>>>(
        (const __hip_bfloat16*)d_in[1], (const __hip_bfloat16*)d_in[5],
        (const __hip_bfloat16*)d_in[3], (const __hip_bfloat16*)d_in[7],
        (__hip_bfloat16*)pk, flag);
    repack_w<float, 0><<<dim3(256), dim3(256), 0, stream>>>(
        (const float*)d_in[1], (const float*)d_in[5],
        (const float*)d_in[3], (const float*)d_in[7],
        (float*)pk, flag);
    if (ws_size >= kWsFull) {
      float* cpre = (float*)((char*)d_ws + kWsPack);
      cpre_kernel<__hip_bfloat16, 1><<<dim3(kB * kT), dim3(kC), 0, stream>>>(
          (const __hip_bfloat16*)d_in[0], (const __hip_bfloat16*)d_in[2],
          (const __hip_bfloat16*)pk, cpre, flag);
      cpre_kernel<float, 0><<<dim3(kB * kT), dim3(kC), 0, stream>>>(
          (const float*)d_in[0], (const float*)d_in[2],
          (const float*)pk, cpre, flag);
      launch_variant<__hip_bfloat16, 1, 2>(d_in, d_out, flag, pk, cpre, stream);
      launch_variant<float, 0, 2>(d_in, d_out, flag, pk, cpre, stream);
    } else {
      launch_variant<__hip_bfloat16, 1, 1>(d_in, d_out, flag, pk, nullptr, stream);
      launch_variant<float, 0, 1>(d_in, d_out, flag, pk, nullptr, stream);
    }
  } else {
    launch_variant<__hip_bfloat16, 1, 0>(d_in, d_out, flag, nullptr, nullptr, stream);
    launch_variant<float, 0, 0>(d_in, d_out, flag, nullptr, nullptr, stream);
  }
}